// Round 9
// baseline (1329.594 us; speedup 1.0000x reference)
//
#include <hip/hip_runtime.h>
#include <hip/hip_bf16.h>

// GptOss grouped experts, round 9: faithful m201 8-phase port for GEMM1.
// GEMM1: 256x256 tile, BK=64, 8 waves (2Mx4N), per-wave 128x64 (FM=8,FN=4).
// 4 phases/K-tile, each {ds_read subtile + stage ONE half-tile (2 glds) ->
// barrier -> lgkm0 -> setprio1 -> 16 MFMA -> setprio0 -> barrier}; counted
// vmcnt(4) once per K-tile. Half staging order: ph0 B-hi(t+1), ph1 A-hi(t+1),
// ph2 B-lo(t+2), ph3 A-lo(t+2) (each provably race-free vs reads).
// N1=5760 padded to 23 n-tiles of 256 via clamped B-row staging + predicated
// bias/store. GEMM2 + 3 cvt kernels: exactly R7 (verified 1178 total).

#define TT   16384
#define DIM_ 2880
#define HID_ 2880
#define NE   8
#define TPE  2048
#define KDIM 2880
#define NT   45       // KDIM / 64
#define NB1  5760     // real N of gemm1
#define NT1P 23       // padded n-tiles (5888/256)

typedef __attribute__((ext_vector_type(8))) short short8;
typedef __attribute__((ext_vector_type(4))) float f32x4;

__device__ __forceinline__ unsigned short f2bf(float f) {
  unsigned u = __builtin_bit_cast(unsigned, f);
  u += 0x7fffu + ((u >> 16) & 1u);   // round-to-nearest-even
  return (unsigned short)(u >> 16);
}

__global__ void __launch_bounds__(256) cvt_f32_bf16(const float* __restrict__ src,
                                                    unsigned short* __restrict__ dst,
                                                    long n) {
  long i = ((long)blockIdx.x * 256 + threadIdx.x) * 8;
  if (i >= n) return;
  float4 a = *(const float4*)(src + i);
  float4 b = *(const float4*)(src + i + 4);
  union { unsigned short u[8]; short8 v; } r;
  r.u[0] = f2bf(a.x); r.u[1] = f2bf(a.y); r.u[2] = f2bf(a.z); r.u[3] = f2bf(a.w);
  r.u[4] = f2bf(b.x); r.u[5] = f2bf(b.y); r.u[6] = f2bf(b.z); r.u[7] = f2bf(b.w);
  *(short8*)(dst + i) = r.v;
}

#define GLDS(gsrc, ldst) \
  __builtin_amdgcn_global_load_lds( \
      (const __attribute__((address_space(1))) unsigned int*)(gsrc), \
      (__attribute__((address_space(3))) unsigned int*)(ldst), 16, 0, 0)

#define MFMA(a, b, c) __builtin_amdgcn_mfma_f32_16x16x32_bf16(a, b, c, 0, 0, 0)

// ---------------- GEMM1: 8-phase m201 schedule + fused bias/SwiGLU ----------
__global__ void __launch_bounds__(512, 2) gemm1_8ph(const unsigned short* __restrict__ A,
                                                    const unsigned short* __restrict__ B,
                                                    const float* __restrict__ bias,
                                                    unsigned short* __restrict__ ha) {
  __shared__ unsigned short As[2][256 * 64];   // two 128x64 half-blocks per buf
  __shared__ unsigned short Bs[2][256 * 64];

  const int tid  = threadIdx.x;
  const int lane = tid & 63;
  const int wid  = tid >> 6;
  const int wr   = wid >> 2;        // 0..1
  const int wc   = wid & 3;         // 0..3
  const int e    = blockIdx.z;

  // T1: per-expert bijective XCD swizzle (per_e = 8*23 = 184, %8 == 0)
  const int per_e = 8 * NT1P;
  const int bid   = blockIdx.x;
  const int swz   = (bid & 7) * (per_e >> 3) + (bid >> 3);
  const int m0    = (swz / NT1P) * 256;
  const int n0    = (swz % NT1P) * 256;

  const unsigned short* Ae = A + (size_t)e * TPE * KDIM;
  const unsigned short* Be = B + (size_t)e * NB1 * KDIM;

  // staging: half-tile = 128 rows x 64 k (16 KB); per thread 2 x 16B issues.
  // wave w covers rows [w*16, w*16+16); T2 inverse-swizzle on source chunk.
  const int srow0 = (wid << 4) + (lane >> 3);       // i=0 row within half

  auto stA = [&](int buf, int kt, int h) {
#pragma unroll
    for (int i = 0; i < 2; ++i) {
      const int row = srow0 + i * 8;                // 0..127
      const int sc  = ((lane & 7) ^ (row & 7)) << 3;
      GLDS(Ae + (size_t)(m0 + h * 128 + row) * KDIM + kt * 64 + sc,
           &As[buf][h * 8192 + ((wid << 4) + i * 8) * 64 + lane * 8]);
    }
  };
  auto stB = [&](int buf, int kt, int h) {
#pragma unroll
    for (int i = 0; i < 2; ++i) {
      const int row = srow0 + i * 8;
      int gr = n0 + h * 128 + row;
      gr = gr < NB1 ? gr : NB1 - 1;                 // clamp pad region (finite junk)
      const int sc = ((lane & 7) ^ (row & 7)) << 3;
      GLDS(Be + (size_t)gr * KDIM + kt * 64 + sc,
           &Bs[buf][h * 8192 + ((wid << 4) + i * 8) * 64 + lane * 8]);
    }
  };

  // fragment-read addressing (swizzled), bytes; half-block layout [128][64]
  const int arow = wr * 16384 + (lane & 15) * 128;                       // + fm*2048
  const int brow = (wc >> 1) * 16384 + ((wc & 1) * 64 + (lane & 15)) * 128; // + fn*2048
  const int swzb = (lane & 7) << 4;
  const int kb   = ((lane >> 4) & 3) * 16;
  const int c0 = kb ^ swzb;
  const int c1 = (64 + kb) ^ swzb;

  f32x4 acc[8][4] = {};

  // prologue: B-lo(0) A-lo(0) B-hi(0) A-hi(0) B-lo(1) A-lo(1); wait tile 0.
  stB(0, 0, 0); stA(0, 0, 0); stB(0, 0, 1); stA(0, 0, 1);
  stB(1, 1, 0); stA(1, 1, 0);
  asm volatile("s_waitcnt vmcnt(4)" ::: "memory");
  __builtin_amdgcn_s_barrier();

  for (int t = 0; t < NT; ++t) {
    const int cur = t & 1;
    const char* aB = (const char*)&As[cur][0] + arow;
    const char* bB = (const char*)&Bs[cur][0] + brow;
    const bool s1 = (t + 1 < NT), s2 = (t + 2 < NT);

    short8 a0[4], a1[4], b0[4], b1[4];

    // ---- ph0: read A fm0-3 + B fn0-1 (12 ds); stage B-hi(t+1); Q(lo,lo)
#pragma unroll
    for (int i = 0; i < 4; ++i) {
      a0[i] = *(const short8*)(aB + i * 2048 + c0);
      a1[i] = *(const short8*)(aB + i * 2048 + c1);
    }
#pragma unroll
    for (int f = 0; f < 2; ++f) {
      b0[f] = *(const short8*)(bB + f * 2048 + c0);
      b1[f] = *(const short8*)(bB + f * 2048 + c1);
    }
    if (s1) stB(cur ^ 1, t + 1, 1);
    asm volatile("s_waitcnt lgkmcnt(8)" ::: "memory");
    __builtin_amdgcn_s_barrier();
    asm volatile("s_waitcnt lgkmcnt(0)" ::: "memory");
    __builtin_amdgcn_s_setprio(1);
#pragma unroll
    for (int f = 0; f < 2; ++f)
#pragma unroll
      for (int i = 0; i < 4; ++i) {
        acc[i][f] = MFMA(a0[i], b0[f], acc[i][f]);
        acc[i][f] = MFMA(a1[i], b1[f], acc[i][f]);
      }
    __builtin_amdgcn_s_setprio(0);
    __builtin_amdgcn_s_barrier();

    // ---- ph1: read B fn2-3 (4 ds); stage A-hi(t+1); Q(lo,hi)
#pragma unroll
    for (int f = 2; f < 4; ++f) {
      b0[f] = *(const short8*)(bB + f * 2048 + c0);
      b1[f] = *(const short8*)(bB + f * 2048 + c1);
    }
    if (s1) stA(cur ^ 1, t + 1, 1);
    __builtin_amdgcn_s_barrier();
    asm volatile("s_waitcnt lgkmcnt(0)" ::: "memory");
    __builtin_amdgcn_s_setprio(1);
#pragma unroll
    for (int f = 2; f < 4; ++f)
#pragma unroll
      for (int i = 0; i < 4; ++i) {
        acc[i][f] = MFMA(a0[i], b0[f], acc[i][f]);
        acc[i][f] = MFMA(a1[i], b1[f], acc[i][f]);
      }
    __builtin_amdgcn_s_setprio(0);
    __builtin_amdgcn_s_barrier();
    // B-lo and B-hi of buf cur fully read by all waves from here

    // ---- ph2: read A fm4-7 (8 ds); stage B-lo(t+2); Q(hi,hi)
#pragma unroll
    for (int i = 0; i < 4; ++i) {
      a0[i] = *(const short8*)(aB + (4 + i) * 2048 + c0);
      a1[i] = *(const short8*)(aB + (4 + i) * 2048 + c1);
    }
    if (s2) stB(cur, t + 2, 0);
    __builtin_amdgcn_s_barrier();
    asm volatile("s_waitcnt lgkmcnt(0)" ::: "memory");
    __builtin_amdgcn_s_setprio(1);
#pragma unroll
    for (int f = 2; f < 4; ++f)
#pragma unroll
      for (int i = 0; i < 4; ++i) {
        acc[4 + i][f] = MFMA(a0[i], b0[f], acc[4 + i][f]);
        acc[4 + i][f] = MFMA(a1[i], b1[f], acc[4 + i][f]);
      }
    __builtin_amdgcn_s_setprio(0);
    __builtin_amdgcn_s_barrier();
    // A-lo and A-hi of buf cur fully read by all waves from here

    // ---- ph3: no ds; stage A-lo(t+2); Q(hi,lo); counted vmcnt at boundary
    if (s2) stA(cur, t + 2, 0);
    __builtin_amdgcn_s_setprio(1);
#pragma unroll
    for (int f = 0; f < 2; ++f)
#pragma unroll
      for (int i = 0; i < 4; ++i) {
        acc[4 + i][f] = MFMA(a0[i], b0[f], acc[4 + i][f]);
        acc[4 + i][f] = MFMA(a1[i], b1[f], acc[4 + i][f]);
      }
    __builtin_amdgcn_s_setprio(0);
    if (s2) asm volatile("s_waitcnt vmcnt(4)" ::: "memory");
    else    asm volatile("s_waitcnt vmcnt(0)" ::: "memory");
    __builtin_amdgcn_s_barrier();
  }

  // ---- epilogue: bias + SwiGLU -> ha (bf16), predicated on col < 5760
  const float* be = bias + (size_t)e * NB1;
  unsigned short* hae = ha + (size_t)e * TPE * HID_;
#pragma unroll
  for (int fm = 0; fm < 8; ++fm)
#pragma unroll
    for (int fn = 0; fn < 4; ++fn) {
      const int col = n0 + wc * 64 + fn * 16 + (lane & 15);
      const bool ok = col < NB1;
      const float bc = ok ? be[col] : 0.0f;
#pragma unroll
      for (int j = 0; j < 4; ++j) {
        const int row = m0 + wr * 128 + fm * 16 + (lane >> 4) * 4 + j;
        float v = acc[fm][fn][j] + bc;
        float p = __shfl_xor(v, 1);   // partner column (all lanes execute)
        if (!(lane & 1) && ok) {
          float g  = fminf(v, 7.0f);
          float l2 = fminf(fmaxf(p, -7.0f), 7.0f);
          float act = g / (1.0f + __expf(-1.702f * g)) * (l2 + 1.0f);
          hae[(size_t)row * HID_ + (col >> 1)] = f2bf(act);
        }
      }
    }
}

// ---------------- GEMM2: R7's verified 2-barrier counted-vmcnt kernel -------
__global__ void __launch_bounds__(512, 2) gemm2k(const unsigned short* __restrict__ A,
                                                 const unsigned short* __restrict__ B,
                                                 const float* __restrict__ bias,
                                                 float* __restrict__ Cout,
                                                 int M, int N) {
  __shared__ unsigned short As[2][256 * 64];
  __shared__ unsigned short Bs[2][320 * 64];

  const int tid  = threadIdx.x;
  const int lane = tid & 63;
  const int wid  = tid >> 6;
  const int wr   = wid >> 2;
  const int wc   = wid & 3;
  const int e    = blockIdx.z;

  const int ntn   = N / 320;
  const int ntm   = M / 256;
  const int per_e = ntn * ntm;
  const int bid   = blockIdx.x;
  const int swz   = (bid & 7) * (per_e >> 3) + (bid >> 3);
  const int m0    = (swz / ntn) * 256;
  const int n0    = (swz % ntn) * 320;

  const int srow = tid >> 3;
  const int scol = ((tid & 7) ^ (srow & 7)) << 3;
  const unsigned short* Aexp = A + ((size_t)e * M + m0 + srow) * KDIM + scol;
  const unsigned short* Bexp = B + ((size_t)e * N + n0 + srow) * KDIM + scol;

  auto stage = [&](int buf, int kt) {
    const unsigned short* asrc = Aexp + (size_t)kt * 64;
#pragma unroll
    for (int j = 0; j < 4; ++j)
      GLDS(asrc + (size_t)(j * 64) * KDIM, &As[buf][j * 4096 + tid * 8]);
    const unsigned short* bsrc = Bexp + (size_t)kt * 64;
#pragma unroll
    for (int j = 0; j < 5; ++j)
      GLDS(bsrc + (size_t)(j * 64) * KDIM, &Bs[buf][j * 4096 + tid * 8]);
  };

  const int arow = (wr * 128 + (lane & 15)) * 128;
  const int brow = (wc * 80  + (lane & 15)) * 128;
  const int swzb = (lane & 7) << 4;
  const int kb   = ((lane >> 4) & 3) * 16;
  const int c0 = kb ^ swzb;
  const int c1 = (64 + kb) ^ swzb;

  f32x4 acc[8][5] = {};

  stage(0, 0);
  stage(1, 1);
  asm volatile("s_waitcnt vmcnt(9)" ::: "memory");
  __builtin_amdgcn_s_barrier();

  for (int t = 0; t < NT; ++t) {
    const int cur = t & 1;
    const char* aB = (const char*)(&As[cur][0]) + arow;
    const char* bB = (const char*)(&Bs[cur][0]) + brow;

    short8 a0[8], a1[8], b0[5], b1[5];
#pragma unroll
    for (int fm = 0; fm < 8; ++fm) {
      a0[fm] = *(const short8*)(aB + fm * 2048 + c0);
      a1[fm] = *(const short8*)(aB + fm * 2048 + c1);
    }
#pragma unroll
    for (int fn = 0; fn < 5; ++fn) {
      b0[fn] = *(const short8*)(bB + fn * 2048 + c0);
      b1[fn] = *(const short8*)(bB + fn * 2048 + c1);
    }

#pragma unroll
    for (int fn = 0; fn < 5; ++fn)
#pragma unroll
      for (int fm = 0; fm < 8; ++fm)
        acc[fm][fn] = MFMA(a0[fm], b0[fn], acc[fm][fn]);

    asm volatile("s_waitcnt lgkmcnt(0)" ::: "memory");
    __builtin_amdgcn_s_barrier();

    const bool more = (t + 2 < NT);
    if (more) stage(cur, t + 2);

    __builtin_amdgcn_s_setprio(1);
#pragma unroll
    for (int fn = 0; fn < 5; ++fn)
#pragma unroll
      for (int fm = 0; fm < 8; ++fm)
        acc[fm][fn] = MFMA(a1[fm], b1[fn], acc[fm][fn]);
    __builtin_amdgcn_s_setprio(0);

    if (more) asm volatile("s_waitcnt vmcnt(9)" ::: "memory");
    else      asm volatile("s_waitcnt vmcnt(0)" ::: "memory");
    __builtin_amdgcn_s_barrier();
  }

  const float* be = bias + (size_t)e * N;
  float* out = Cout + (size_t)e * (size_t)M * N;
#pragma unroll
  for (int fm = 0; fm < 8; ++fm)
#pragma unroll
    for (int fn = 0; fn < 5; ++fn) {
      const int col = n0 + wc * 80 + fn * 16 + (lane & 15);
      const float bc = be[col];
#pragma unroll
      for (int j = 0; j < 4; ++j) {
        const int row = m0 + wr * 128 + fm * 16 + (lane >> 4) * 4 + j;
        out[(size_t)row * N + col] = acc[fm][fn][j] + bc;
      }
    }
}

extern "C" void kernel_launch(void* const* d_in, const int* in_sizes, int n_in,
                              void* d_out, int out_size, void* d_ws, size_t ws_size,
                              hipStream_t stream) {
  const float* x  = (const float*)d_in[0];
  // d_in[1] = num_tokens_per_expert: fixed T/E split (reference ignores it)
  const float* w1 = (const float*)d_in[2];
  const float* b1 = (const float*)d_in[3];
  const float* w2 = (const float*)d_in[4];
  const float* b2 = (const float*)d_in[5];

  unsigned short* xb  = (unsigned short*)d_ws;
  unsigned short* w1b = xb  + (size_t)TT * DIM_;
  unsigned short* w2b = w1b + (size_t)NE * 2 * HID_ * DIM_;
  unsigned short* ha  = w2b + (size_t)NE * DIM_ * HID_;

  const long nx = (long)TT * DIM_;
  const long n1 = (long)NE * 2 * HID_ * DIM_;
  const long n2 = (long)NE * DIM_ * HID_;
  cvt_f32_bf16<<<(int)(nx / 2048), 256, 0, stream>>>(x,  xb,  nx);
  cvt_f32_bf16<<<(int)(n1 / 2048), 256, 0, stream>>>(w1, w1b, n1);
  cvt_f32_bf16<<<(int)(n2 / 2048), 256, 0, stream>>>(w2, w2b, n2);

  // GEMM1 + bias + swiglu -> ha (bf16 [E][2048][2880]); padded n-tiling 23x256
  dim3 g1(8 * NT1P, 1, NE);                    // 184 per expert
  gemm1_8ph<<<g1, 512, 0, stream>>>(xb, w1b, b1, ha);

  // GEMM2 + bias -> out (fp32 [T][2880])
  dim3 g2((DIM_ / 320) * (TPE / 256), 1, NE);  // 72 per expert
  gemm2k<<<g2, 512, 0, stream>>>(ha, w2b, b2, (float*)d_out, TPE, DIM_);
}

// Round 10
// 1159.946 us; speedup vs baseline: 1.1463x; 1.1463x over previous
//
#include <hip/hip_runtime.h>
#include <hip/hip_bf16.h>

// GptOss grouped experts, round 10: R7 (verified best: 1178 us; gemm1 631,
// gemm2 297, cvt ~250) with ONE isolated change: 2D XCD chunking for gemm1.
// Old T1 chunk = one m-row per XCD (A 1.5MB L2-hit, B 33MB streamed via L3
// per chunk -> 2.1GB L3-side + L3 capacity thrash -> 1.1GB HBM refetch).
// New: per-expert 8x18 tile grid partitioned 4x2 into chunks of 2m x 9n,
// pair-interleaved traversal (consecutive blocks alternate m within same n)
// so each 1.84MB B slice is L2-resident for both consumers.
// L3-side bytes/chunk 34.5 -> 19.5 MB. Sync structure byte-identical to R7.

#define TT   16384
#define DIM_ 2880
#define HID_ 2880
#define NE   8
#define TPE  2048
#define KDIM 2880
#define NT   45     // KDIM / 64

typedef __attribute__((ext_vector_type(8))) short short8;
typedef __attribute__((ext_vector_type(4))) float f32x4;

__device__ __forceinline__ unsigned short f2bf(float f) {
  unsigned u = __builtin_bit_cast(unsigned, f);
  u += 0x7fffu + ((u >> 16) & 1u);   // round-to-nearest-even
  return (unsigned short)(u >> 16);
}

__global__ void __launch_bounds__(256) cvt_f32_bf16(const float* __restrict__ src,
                                                    unsigned short* __restrict__ dst,
                                                    long n) {
  long i = ((long)blockIdx.x * 256 + threadIdx.x) * 8;
  if (i >= n) return;
  float4 a = *(const float4*)(src + i);
  float4 b = *(const float4*)(src + i + 4);
  union { unsigned short u[8]; short8 v; } r;
  r.u[0] = f2bf(a.x); r.u[1] = f2bf(a.y); r.u[2] = f2bf(a.z); r.u[3] = f2bf(a.w);
  r.u[4] = f2bf(b.x); r.u[5] = f2bf(b.y); r.u[6] = f2bf(b.z); r.u[7] = f2bf(b.w);
  *(short8*)(dst + i) = r.v;
}

#define GLDS(gsrc, ldst) \
  __builtin_amdgcn_global_lds( \
      (const __attribute__((address_space(1))) unsigned int*)(gsrc), \
      (__attribute__((address_space(3))) unsigned int*)(ldst), 16, 0, 0)
#undef GLDS
#define GLDS(gsrc, ldst) \
  __builtin_amdgcn_global_load_lds( \
      (const __attribute__((address_space(1))) unsigned int*)(gsrc), \
      (__attribute__((address_space(3))) unsigned int*)(ldst), 16, 0, 0)

// C = A(MxK) * B(NxK)^T, bf16 in, fp32 accum. BM=256, BN=320, BK=64.
// 512 threads = 8 waves (2M x 4N); per-wave 128x80 (FM=8, FN=5).
// CH2D: gemm1's 2m x 9n pair-interleaved XCD chunking (requires ntm=8,ntn=18).
// LDS: dbuf x (A 32KB + B 40KB) = 144 KB.
template<bool FUSE_SWIGLU, bool CH2D>
__global__ void __launch_bounds__(512, 2) gemm8(const unsigned short* __restrict__ A,
                                                const unsigned short* __restrict__ B,
                                                const float* __restrict__ bias,
                                                void* __restrict__ Cout,
                                                int M, int N) {
  __shared__ unsigned short As[2][256 * 64];
  __shared__ unsigned short Bs[2][320 * 64];

  const int tid  = threadIdx.x;
  const int lane = tid & 63;
  const int wid  = tid >> 6;
  const int wr   = wid >> 2;        // 0..1
  const int wc   = wid & 3;         // 0..3
  const int e    = blockIdx.z;
  const int bid  = blockIdx.x;

  int m0, n0;
  if constexpr (CH2D) {
    // 8x18 tile grid, 4x2 chunks of 2m x 9n; bid&7 = XCD chunk, bid>>3 = local.
    const int c  = bid & 7;         // chunk id
    const int l  = bid >> 3;        // 0..17, dispatch-consecutive on this XCD
    const int cm = c >> 1;          // 0..3
    const int cn = c & 1;           // 0..1
    m0 = (cm * 2 + (l & 1)) * 256;  // pair-interleave: alternate m fastest
    n0 = (cn * 9 + (l >> 1)) * 320; // same n for consecutive block pairs
  } else {
    const int ntn   = N / 320;
    const int per_e = ntn * (M / 256);
    const int swz   = (bid & 7) * (per_e >> 3) + (bid >> 3);
    m0 = (swz / ntn) * 256;
    n0 = (swz % ntn) * 320;
  }

  // staging: 8 lanes/row, 16B/lane; T2 inverse-swizzle on source column
  const int srow = tid >> 3;                         // 0..63
  const int scol = ((tid & 7) ^ (srow & 7)) << 3;    // elements
  const unsigned short* Aexp = A + ((size_t)e * M + m0 + srow) * KDIM + scol;
  const unsigned short* Bexp = B + ((size_t)e * N + n0 + srow) * KDIM + scol;

  auto stage = [&](int buf, int kt) {
    const unsigned short* asrc = Aexp + (size_t)kt * 64;
#pragma unroll
    for (int j = 0; j < 4; ++j)
      GLDS(asrc + (size_t)(j * 64) * KDIM, &As[buf][j * 4096 + tid * 8]);
    const unsigned short* bsrc = Bexp + (size_t)kt * 64;
#pragma unroll
    for (int j = 0; j < 5; ++j)
      GLDS(bsrc + (size_t)(j * 64) * KDIM, &Bs[buf][j * 4096 + tid * 8]);
  };

  // fragment-read addressing (swizzled), byte offsets; row stride 128 B
  const int arow = (wr * 128 + (lane & 15)) * 128;
  const int brow = (wc * 80  + (lane & 15)) * 128;
  const int swzb = (lane & 7) << 4;
  const int kb   = ((lane >> 4) & 3) * 16;
  const int c0 = kb ^ swzb;          // kk=0
  const int c1 = (64 + kb) ^ swzb;   // kk=1

  f32x4 acc[8][5] = {};

  // prologue: tiles 0,1 staged (9 loads each); wait tile 0.
  stage(0, 0);
  stage(1, 1);
  asm volatile("s_waitcnt vmcnt(9)" ::: "memory");
  __builtin_amdgcn_s_barrier();

  for (int t = 0; t < NT; ++t) {
    const int cur = t & 1;
    const char* aB = (const char*)(&As[cur][0]) + arow;
    const char* bB = (const char*)(&Bs[cur][0]) + brow;

    short8 a0[8], a1[8], b0[5], b1[5];
#pragma unroll
    for (int fm = 0; fm < 8; ++fm) {
      a0[fm] = *(const short8*)(aB + fm * 2048 + c0);
      a1[fm] = *(const short8*)(aB + fm * 2048 + c1);
    }
#pragma unroll
    for (int fn = 0; fn < 5; ++fn) {
      b0[fn] = *(const short8*)(bB + fn * 2048 + c0);
      b1[fn] = *(const short8*)(bB + fn * 2048 + c1);
    }

    // kk=0 MFMAs overlap kk=1 ds_reads (compiler counted lgkmcnt)
#pragma unroll
    for (int fn = 0; fn < 5; ++fn)
#pragma unroll
      for (int fm = 0; fm < 8; ++fm)
        acc[fm][fn] = __builtin_amdgcn_mfma_f32_16x16x32_bf16(a0[fm], b0[fn], acc[fm][fn], 0, 0, 0);

    // all our ds_reads done -> buffer free; barrier makes it true for all waves
    asm volatile("s_waitcnt lgkmcnt(0)" ::: "memory");
    __builtin_amdgcn_s_barrier();

    const bool more = (t + 2 < NT);
    if (more) stage(cur, t + 2);     // overwrite vacated buffer

    __builtin_amdgcn_s_setprio(1);
#pragma unroll
    for (int fn = 0; fn < 5; ++fn)
#pragma unroll
      for (int fm = 0; fm < 8; ++fm)
        acc[fm][fn] = __builtin_amdgcn_mfma_f32_16x16x32_bf16(a1[fm], b1[fn], acc[fm][fn], 0, 0, 0);
    __builtin_amdgcn_s_setprio(0);

    // counted vmcnt: wait tile t+1 complete, leave tile t+2's 9 loads in flight
    if (more) asm volatile("s_waitcnt vmcnt(9)" ::: "memory");
    else      asm volatile("s_waitcnt vmcnt(0)" ::: "memory");
    __builtin_amdgcn_s_barrier();
  }

  // ---- epilogue
  const float* be = bias + (size_t)e * N;
  if constexpr (FUSE_SWIGLU) {
    unsigned short* ha = (unsigned short*)Cout + (size_t)e * M * (N >> 1);
#pragma unroll
    for (int fm = 0; fm < 8; ++fm)
#pragma unroll
      for (int fn = 0; fn < 5; ++fn) {
        const int col = n0 + wc * 80 + fn * 16 + (lane & 15);
        const float bc = be[col];
#pragma unroll
        for (int j = 0; j < 4; ++j) {
          const int row = m0 + wr * 128 + fm * 16 + (lane >> 4) * 4 + j;
          float v = acc[fm][fn][j] + bc;
          float p = __shfl_xor(v, 1);   // partner column (all lanes execute)
          if (!(lane & 1)) {
            float g  = fminf(v, 7.0f);
            float l2 = fminf(fmaxf(p, -7.0f), 7.0f);
            float act = g / (1.0f + __expf(-1.702f * g)) * (l2 + 1.0f);
            ha[(size_t)row * (N >> 1) + (col >> 1)] = f2bf(act);
          }
        }
      }
  } else {
    float* out = (float*)Cout + (size_t)e * M * N;
#pragma unroll
    for (int fm = 0; fm < 8; ++fm)
#pragma unroll
      for (int fn = 0; fn < 5; ++fn) {
        const int col = n0 + wc * 80 + fn * 16 + (lane & 15);
        const float bc = be[col];
#pragma unroll
        for (int j = 0; j < 4; ++j) {
          const int row = m0 + wr * 128 + fm * 16 + (lane >> 4) * 4 + j;
          out[(size_t)row * N + col] = acc[fm][fn][j] + bc;
        }
      }
  }
}

extern "C" void kernel_launch(void* const* d_in, const int* in_sizes, int n_in,
                              void* d_out, int out_size, void* d_ws, size_t ws_size,
                              hipStream_t stream) {
  const float* x  = (const float*)d_in[0];
  // d_in[1] = num_tokens_per_expert: fixed T/E split (reference ignores it)
  const float* w1 = (const float*)d_in[2];
  const float* b1 = (const float*)d_in[3];
  const float* w2 = (const float*)d_in[4];
  const float* b2 = (const float*)d_in[5];

  unsigned short* xb  = (unsigned short*)d_ws;
  unsigned short* w1b = xb  + (size_t)TT * DIM_;
  unsigned short* w2b = w1b + (size_t)NE * 2 * HID_ * DIM_;
  unsigned short* ha  = w2b + (size_t)NE * DIM_ * HID_;

  const long nx = (long)TT * DIM_;
  const long n1 = (long)NE * 2 * HID_ * DIM_;
  const long n2 = (long)NE * DIM_ * HID_;
  cvt_f32_bf16<<<(int)(nx / 2048), 256, 0, stream>>>(x,  xb,  nx);
  cvt_f32_bf16<<<(int)(n1 / 2048), 256, 0, stream>>>(w1, w1b, n1);
  cvt_f32_bf16<<<(int)(n2 / 2048), 256, 0, stream>>>(w2, w2b, n2);

  // GEMM1 + bias + swiglu -> ha (bf16 [E][2048][2880]); 2D XCD chunking
  dim3 g1((5760 / 320) * (TPE / 256), 1, NE);   // 18*8 = 144 per expert
  gemm8<true, true><<<g1, 512, 0, stream>>>(xb, w1b, b1, ha, TPE, 5760);

  // GEMM2 + bias -> out (fp32 [T][2880]); R7 swizzle (9x8 grid, no 2x9 split)
  dim3 g2((DIM_ / 320) * (TPE / 256), 1, NE);   // 9*8 = 72 per expert
  gemm8<false, false><<<g2, 512, 0, stream>>>(ha, w2b, b2, (float*)d_out, TPE, DIM_);
}